// Round 5
// baseline (210.832 us; speedup 1.0000x reference)
//
#include <hip/hip_runtime.h>
#include <hip/hip_bf16.h>
#include <math.h>

// Problem: B=1, N=512, C=256, fp32 in/out.
// out[i,c] = sum_j softmax_j( w[i,j,c] ) * v[j,c],  w = mish(LN(Kp[j]-Qp[i])) @ W2  (+b2 cancels)
// Kp = mish(LN(feat@Wk+bk)) @ W1 + b1 ; Qp = mish(LN(feat@Wq+bq)) @ W1 ; v = feat@Wv+bv
// R5: 32x32x16 MFMA, 8-wave blocks, resident-B = 64 VGPR, __launch_bounds__(512,4)
// to force 2 resident blocks/CU (16 waves/CU). T fragment-major in LDS (1 b128/kstep).

#define N_ 512
#define C_ 256
#define NCHUNK 2
#define JPB (N_ / NCHUNK)   // 256 j's per block
#define JT 32               // j rows per tile

typedef short s8v __attribute__((ext_vector_type(8)));
typedef float f4v __attribute__((ext_vector_type(4)));
typedef float f16v __attribute__((ext_vector_type(16)));
typedef unsigned int u4v __attribute__((ext_vector_type(4)));

__device__ __forceinline__ unsigned short f2bf(float x) {
  union { __hip_bfloat16 h; unsigned short u; } cv;
  cv.h = __float2bfloat16(x);
  return cv.u;
}

__device__ __forceinline__ float mish_f(float x) {
  // mish(x) = x*tanh(softplus(x)) = x*(y^2-1)/(y^2+1), y = 1+e^x
  if (x > 25.f) return x;  // tanh saturated to 1.0 in fp32
  float y = 1.f + __expf(x);
  float y2 = y * y;
  return x * __fdividef(y2 - 1.f, y2 + 1.f);
}

// block (256 thr) reduction of two values, result broadcast to all threads
__device__ __forceinline__ void blockReduce2(float& a, float& b, float* red) {
  #pragma unroll
  for (int m = 1; m < 64; m <<= 1) { a += __shfl_xor(a, m); b += __shfl_xor(b, m); }
  int lane = threadIdx.x & 63, w = threadIdx.x >> 6;
  if (lane == 0) { red[w] = a; red[4 + w] = b; }
  __syncthreads();
  a = red[0] + red[1] + red[2] + red[3];
  b = red[4] + red[5] + red[6] + red[7];
  __syncthreads();
}

// ---------------- prep: dist, v, Qp, Kp (fp32) ----------------
__global__ void __launch_bounds__(256) prep_kernel(
    const float* __restrict__ feat,
    const float* __restrict__ Wq, const float* __restrict__ bq,
    const float* __restrict__ gq, const float* __restrict__ bgq,
    const float* __restrict__ Wk, const float* __restrict__ bk,
    const float* __restrict__ gk, const float* __restrict__ bgk,
    const float* __restrict__ Wv, const float* __restrict__ bv,
    const float* __restrict__ W1, const float* __restrict__ b1,
    float* __restrict__ dist, float* __restrict__ vout,
    float* __restrict__ Qp, float* __restrict__ Kp) {
  const int tid = threadIdx.x;
  const int r0 = blockIdx.x * 4;
  __shared__ float fL[4][C_];
  __shared__ float xq[4][C_];
  __shared__ float xk[4][C_];
  __shared__ float red[8];

  #pragma unroll
  for (int r = 0; r < 4; ++r) fL[r][tid] = feat[(r0 + r) * C_ + tid];
  __syncthreads();

  // dist = (sum |feat| > 0)
  {
    float a = fabsf(fL[0][tid]), b = fabsf(fL[1][tid]);
    blockReduce2(a, b, red);
    if (tid == 0) { dist[r0 + 0] = a > 0.f ? 1.f : 0.f; dist[r0 + 1] = b > 0.f ? 1.f : 0.f; }
    a = fabsf(fL[2][tid]); b = fabsf(fL[3][tid]);
    blockReduce2(a, b, red);
    if (tid == 0) { dist[r0 + 2] = a > 0.f ? 1.f : 0.f; dist[r0 + 3] = b > 0.f ? 1.f : 0.f; }
  }

  // q/k/v matmuls (fp32)
  float aq[4] = {0,0,0,0}, ak[4] = {0,0,0,0}, av[4] = {0,0,0,0};
  for (int cp = 0; cp < C_; ++cp) {
    float wq = Wq[cp * C_ + tid], wk = Wk[cp * C_ + tid], wv = Wv[cp * C_ + tid];
    #pragma unroll
    for (int r = 0; r < 4; ++r) {
      float f = fL[r][cp];
      aq[r] += f * wq; ak[r] += f * wk; av[r] += f * wv;
    }
  }
  {
    float bvv = bv[tid];
    #pragma unroll
    for (int r = 0; r < 4; ++r) vout[(r0 + r) * C_ + tid] = av[r] + bvv;
  }

  const float bqv = bq[tid], bkv = bk[tid];
  const float gqv = gq[tid], bgqv = bgq[tid], gkv = gk[tid], bgkv = bgk[tid];
  for (int r = 0; r < 4; ++r) {
    float qv = aq[r] + bqv, kv = ak[r] + bkv;
    float s1 = qv, s2 = qv * qv;
    blockReduce2(s1, s2, red);
    float mu = s1 * (1.f / C_);
    float rs = rsqrtf(s2 * (1.f / C_) - mu * mu + 1e-5f);
    xq[r][tid] = mish_f((qv - mu) * rs * gqv + bgqv);
    s1 = kv; s2 = kv * kv;
    blockReduce2(s1, s2, red);
    mu = s1 * (1.f / C_);
    rs = rsqrtf(s2 * (1.f / C_) - mu * mu + 1e-5f);
    xk[r][tid] = mish_f((kv - mu) * rs * gkv + bgkv);
  }
  __syncthreads();

  // Qp = q@W1, Kp = k@W1 + b1
  float pq[4] = {0,0,0,0}, pk[4] = {0,0,0,0};
  for (int cp = 0; cp < C_; ++cp) {
    float w1 = W1[cp * C_ + tid];
    #pragma unroll
    for (int r = 0; r < 4; ++r) { pq[r] += xq[r][cp] * w1; pk[r] += xk[r][cp] * w1; }
  }
  const float b1v = b1[tid];
  #pragma unroll
  for (int r = 0; r < 4; ++r) {
    Qp[(r0 + r) * C_ + tid] = pq[r];
    Kp[(r0 + r) * C_ + tid] = pk[r] + b1v;
  }
}

// ---------------- W2 -> bf16 fragment-linear repack (32x32x16 layout) ----------------
// W2f[((w*16+ks)*64+l)*8+e] = bf16( W2[k][c] ),  k = ks*16 + (l>>5)*8 + e,
// c = w*32 + (l&31).  k-map sigma(hi,e) identical on A and B sides => correct.
__global__ void __launch_bounds__(256) repack_kernel(
    const float* __restrict__ W2, unsigned short* __restrict__ W2f) {
  int idx = blockIdx.x * 256 + threadIdx.x;  // 65536 total
  int e = idx & 7;
  int l = (idx >> 3) & 63;
  int ks = (idx >> 9) & 15;
  int w = idx >> 13;
  int k = ks * 16 + ((l >> 5) << 3) + e;
  int c = (w << 5) + (l & 31);
  W2f[idx] = f2bf(W2[k * C_ + c]);
}

// ---------------- main fused kernel (pass 1 of 2) ----------------
// grid (512, 2): blockIdx.x = i, blockIdx.y = j-chunk (256 j's). 512 thr = 8 waves.
// Per 32-j tile: tphase (R1's verified 16-ch/thread shuffle-LN + mish) -> LDS
// fragment-major bf16 -> barrier -> 16x mfma_32x32x16 (B resident, 64 VGPR)
// -> max-free softmax accumulate -> barrier.
__global__ void __launch_bounds__(512, 4) attn_kernel(
    const float* __restrict__ dist, const float* __restrict__ v,
    const float* __restrict__ Qp, const float* __restrict__ Kp,
    const unsigned short* __restrict__ W2f,
    const float* __restrict__ gw, const float* __restrict__ bw,
    float* __restrict__ pden, float* __restrict__ pacc) {
  const int tid = threadIdx.x;
  const int i = blockIdx.x;
  const int chunk = blockIdx.y;
  const int j0 = chunk * JPB;
  const int lane = tid & 63, wave = tid >> 6;
  const int jg = tid >> 4, g = tid & 15;   // tphase: 32 j-rows x 16 ch/thread
  const int row = lane & 31, hi = lane >> 5;
  const int cw = (wave << 5) + row;        // this lane's output channel

  __shared__ __align__(16) unsigned short T[JT * C_];  // 16 KiB, swizzled
  __shared__ float qpL[C_], gwL[C_], bwL[C_];
  __shared__ float distT[JT];
  char* Tb = reinterpret_cast<char*>(T);

  if (tid < C_) {
    qpL[tid] = Qp[i * C_ + tid];
    gwL[tid] = gw[tid];
    bwL[tid] = bw[tid];
  }

  // resident B fragments: 16 ksteps x 4 VGPR = 64 VGPR (1 ct of 32 channels/wave)
  s8v Bfr[16];
  #pragma unroll
  for (int ks = 0; ks < 16; ++ks)
    Bfr[ks] = *reinterpret_cast<const s8v*>(
        W2f + ((((wave << 4) + ks) * 64 + lane) << 3));

  float den = 0.f, accv = 0.f;
  __syncthreads();  // qpL/gwL/bwL ready

  for (int jt = 0; jt < JPB / JT; ++jt) {
    const int jb = j0 + jt * JT;
    // ---- T phase: t[j, g*16 .. g*16+15] = mish(LN(Kp[j]-Qp[i])) ----
    {
      const int j = jb + jg;
      const float* kpr = Kp + j * C_ + (g << 4);
      const float* qpr = qpL + (g << 4);
      float d[16];
      float s = 0.f, s2 = 0.f;
      #pragma unroll
      for (int e = 0; e < 16; ++e) {
        float x = kpr[e] - qpr[e];
        d[e] = x; s += x; s2 += x * x;
      }
      #pragma unroll
      for (int mk = 1; mk < 16; mk <<= 1) { s += __shfl_xor(s, mk); s2 += __shfl_xor(s2, mk); }
      float mu = s * (1.f / C_);
      float rs = rsqrtf(s2 * (1.f / C_) - mu * mu + 1e-5f);
      if (g == 0) distT[jg] = dist[j];
      const float* gwp = gwL + (g << 4);
      const float* bwp = bwL + (g << 4);
      u4v p0, p1;
      #pragma unroll
      for (int h = 0; h < 8; ++h) {
        float a = mish_f((d[2*h]   - mu) * rs * gwp[2*h]   + bwp[2*h]);
        float b = mish_f((d[2*h+1] - mu) * rs * gwp[2*h+1] + bwp[2*h+1]);
        // cheap round-to-nearest bf16 (values finite, no NaN path needed)
        unsigned pa = (__float_as_uint(a) + 0x8000u) >> 16;
        unsigned pb = (__float_as_uint(b) + 0x8000u) & 0xFFFF0000u;
        unsigned pk = pa | pb;
        if (h < 4) p0[h] = pk; else p1[h - 4] = pk;
      }
      // fragment-major: byte(row,k) = row*512 + (ks*32 + hi8*16 + e*2) ^ swz,
      // k = ks*16 + hi8*8 + e ; thread's 16 ch = full kstep ks = g.
      const int swz = (jg & 31) << 4;
      const int base = (jg << 9);
      *reinterpret_cast<u4v*>(Tb + base + (((g << 5)     ) ^ swz)) = p0;
      *reinterpret_cast<u4v*>(Tb + base + (((g << 5) + 16) ^ swz)) = p1;
    }
    __syncthreads();

    // ---- MFMA: w[32 x 256] = T @ W2 ; this wave: channels wave*32..+31 ----
    f16v wv;
    #pragma unroll
    for (int r = 0; r < 16; ++r) wv[r] = 0.f;
    #pragma unroll
    for (int ks = 0; ks < 16; ++ks) {
      const int off = (row << 9) + ((((ks << 5) + (hi << 4)) ^ (row << 4)) & 511);
      s8v A = *reinterpret_cast<const s8v*>(Tb + off);
      wv = __builtin_amdgcn_mfma_f32_32x32x16_bf16(A, Bfr[ks], wv, 0, 0, 0);
    }

    // ---- max-free softmax accumulate (D layout: col=lane&31,
    //      row=(r&3)+8*(r>>2)+4*(lane>>5), verified m74/m101) ----
    #pragma unroll
    for (int r = 0; r < 16; ++r) {
      const int jj = (r & 3) + ((r >> 2) << 3) + (hi << 2);
      float e = __expf(fminf(wv[r], 60.f)) * distT[jj];
      den += e;
      accv += e * v[(jb + jj) * C_ + cw];
    }
    __syncthreads();  // protect T/distT before next tile's writes
  }

  // halves hold disjoint j-rows of the same channel: one xor-32 merge
  den  += __shfl_xor(den, 32);
  accv += __shfl_xor(accv, 32);
  if (lane < 32) {
    pden[(chunk * N_ + i) * C_ + cw] = den;
    pacc[(chunk * N_ + i) * C_ + cw] = accv;
  }
}

// ---------------- pass 2: merge chunk partials ----------------
__global__ void __launch_bounds__(256) reduce_kernel(
    const float* __restrict__ dist,
    const float* __restrict__ pden, const float* __restrict__ pacc,
    float* __restrict__ out) {
  const int i = blockIdx.x, c = threadIdx.x;
  float den = 0.f, acc = 0.f;
  #pragma unroll
  for (int ch = 0; ch < NCHUNK; ++ch) {
    den += pden[(ch * N_ + i) * C_ + c];
    acc += pacc[(ch * N_ + i) * C_ + c];
  }
  float o = 0.f;
  if (dist[i] > 0.f && den > 0.f) o = acc / den;
  out[i * C_ + c] = o;
}

extern "C" void kernel_launch(void* const* d_in, const int* in_sizes, int n_in,
                              void* d_out, int out_size, void* d_ws, size_t ws_size,
                              hipStream_t stream) {
  const float* feat = (const float*)d_in[0];
  const float* Wq   = (const float*)d_in[1];
  const float* bq   = (const float*)d_in[2];
  const float* gq   = (const float*)d_in[3];
  const float* bgq  = (const float*)d_in[4];
  const float* Wk   = (const float*)d_in[5];
  const float* bk   = (const float*)d_in[6];
  const float* gk   = (const float*)d_in[7];
  const float* bgk  = (const float*)d_in[8];
  const float* Wv   = (const float*)d_in[9];
  const float* bv   = (const float*)d_in[10];
  const float* W1   = (const float*)d_in[11];
  const float* b1   = (const float*)d_in[12];
  const float* gw   = (const float*)d_in[13];
  const float* bw   = (const float*)d_in[14];
  const float* W2   = (const float*)d_in[15];
  // d_in[16] = b2 : cancels exactly in the j-softmax, unused.

  char* ws = (char*)d_ws;
  float* dist = (float*)(ws + 0);            // 512 f32
  float* v    = (float*)(ws + 0x010000);     // 512 KB
  float* Qp   = (float*)(ws + 0x090000);     // 512 KB
  float* Kp   = (float*)(ws + 0x110000);     // 512 KB
  unsigned short* W2f = (unsigned short*)(ws + 0x190000);  // 128 KB
  float* pden = (float*)(ws + 0x1B0000);     // 2*512*256 f32 = 1 MB
  float* pacc = (float*)(ws + 0x2B0000);     // 1 MB

  hipLaunchKernelGGL(prep_kernel, dim3(128), dim3(256), 0, stream,
                     feat, Wq, bq, gq, bgq, Wk, bk, gk, bgk, Wv, bv, W1, b1,
                     dist, v, Qp, Kp);
  hipLaunchKernelGGL(repack_kernel, dim3(256), dim3(256), 0, stream, W2, W2f);
  hipLaunchKernelGGL(attn_kernel, dim3(512, NCHUNK), dim3(512), 0, stream,
                     dist, v, Qp, Kp, W2f, gw, bw, pden, pacc);
  hipLaunchKernelGGL(reduce_kernel, dim3(512), dim3(256), 0, stream,
                     dist, pden, pacc, (float*)d_out);
}

// Round 6
// 200.583 us; speedup vs baseline: 1.0511x; 1.0511x over previous
//
#include <hip/hip_runtime.h>
#include <hip/hip_bf16.h>
#include <math.h>

// Problem: B=1, N=512, C=256, fp32 in/out.
// out[i,c] = sum_j softmax_j( w[i,j,c] ) * v[j,c],  w = mish(LN(Kp[j]-Qp[i])) @ W2  (+b2 cancels)
// Kp = mish(LN(feat@Wk+bk)) @ W1 + b1 ; Qp = mish(LN(feat@Wq+bq)) @ W1 ; v = feat@Wv+bv
// R6 = R5 (32x32x16 MFMA, 8 waves, 2 blocks/CU, 45% occ) with a conflict-free
// T layout: chunk16B[(ks*2+hi)*32 + row], byte XOR (ks&7)<<4.
//   - MFMA read at fixed ks: lanes cover 1KB contiguous (permuted) -> 0 extra conflicts
//   - T write (thread jg,g -> ks=g): quad=(jg^g)&7 -> 8 consecutive lanes = 8 quads

#define N_ 512
#define C_ 256
#define NCHUNK 2
#define JPB (N_ / NCHUNK)   // 256 j's per block
#define JT 32               // j rows per tile

typedef short s8v __attribute__((ext_vector_type(8)));
typedef float f4v __attribute__((ext_vector_type(4)));
typedef float f16v __attribute__((ext_vector_type(16)));
typedef unsigned int u4v __attribute__((ext_vector_type(4)));

__device__ __forceinline__ unsigned short f2bf(float x) {
  union { __hip_bfloat16 h; unsigned short u; } cv;
  cv.h = __float2bfloat16(x);
  return cv.u;
}

__device__ __forceinline__ float mish_f(float x) {
  // mish(x) = x*tanh(softplus(x)) = x*(y^2-1)/(y^2+1), y = 1+e^x
  if (x > 25.f) return x;  // tanh saturated to 1.0 in fp32
  float y = 1.f + __expf(x);
  float y2 = y * y;
  return x * __fdividef(y2 - 1.f, y2 + 1.f);
}

// block (256 thr) reduction of two values, result broadcast to all threads
__device__ __forceinline__ void blockReduce2(float& a, float& b, float* red) {
  #pragma unroll
  for (int m = 1; m < 64; m <<= 1) { a += __shfl_xor(a, m); b += __shfl_xor(b, m); }
  int lane = threadIdx.x & 63, w = threadIdx.x >> 6;
  if (lane == 0) { red[w] = a; red[4 + w] = b; }
  __syncthreads();
  a = red[0] + red[1] + red[2] + red[3];
  b = red[4] + red[5] + red[6] + red[7];
  __syncthreads();
}

// ---------------- prep: dist, v, Qp, Kp (fp32) ----------------
__global__ void __launch_bounds__(256) prep_kernel(
    const float* __restrict__ feat,
    const float* __restrict__ Wq, const float* __restrict__ bq,
    const float* __restrict__ gq, const float* __restrict__ bgq,
    const float* __restrict__ Wk, const float* __restrict__ bk,
    const float* __restrict__ gk, const float* __restrict__ bgk,
    const float* __restrict__ Wv, const float* __restrict__ bv,
    const float* __restrict__ W1, const float* __restrict__ b1,
    float* __restrict__ dist, float* __restrict__ vout,
    float* __restrict__ Qp, float* __restrict__ Kp) {
  const int tid = threadIdx.x;
  const int r0 = blockIdx.x * 4;
  __shared__ float fL[4][C_];
  __shared__ float xq[4][C_];
  __shared__ float xk[4][C_];
  __shared__ float red[8];

  #pragma unroll
  for (int r = 0; r < 4; ++r) fL[r][tid] = feat[(r0 + r) * C_ + tid];
  __syncthreads();

  // dist = (sum |feat| > 0)
  {
    float a = fabsf(fL[0][tid]), b = fabsf(fL[1][tid]);
    blockReduce2(a, b, red);
    if (tid == 0) { dist[r0 + 0] = a > 0.f ? 1.f : 0.f; dist[r0 + 1] = b > 0.f ? 1.f : 0.f; }
    a = fabsf(fL[2][tid]); b = fabsf(fL[3][tid]);
    blockReduce2(a, b, red);
    if (tid == 0) { dist[r0 + 2] = a > 0.f ? 1.f : 0.f; dist[r0 + 3] = b > 0.f ? 1.f : 0.f; }
  }

  // q/k/v matmuls (fp32)
  float aq[4] = {0,0,0,0}, ak[4] = {0,0,0,0}, av[4] = {0,0,0,0};
  for (int cp = 0; cp < C_; ++cp) {
    float wq = Wq[cp * C_ + tid], wk = Wk[cp * C_ + tid], wv = Wv[cp * C_ + tid];
    #pragma unroll
    for (int r = 0; r < 4; ++r) {
      float f = fL[r][cp];
      aq[r] += f * wq; ak[r] += f * wk; av[r] += f * wv;
    }
  }
  {
    float bvv = bv[tid];
    #pragma unroll
    for (int r = 0; r < 4; ++r) vout[(r0 + r) * C_ + tid] = av[r] + bvv;
  }

  const float bqv = bq[tid], bkv = bk[tid];
  const float gqv = gq[tid], bgqv = bgq[tid], gkv = gk[tid], bgkv = bgk[tid];
  for (int r = 0; r < 4; ++r) {
    float qv = aq[r] + bqv, kv = ak[r] + bkv;
    float s1 = qv, s2 = qv * qv;
    blockReduce2(s1, s2, red);
    float mu = s1 * (1.f / C_);
    float rs = rsqrtf(s2 * (1.f / C_) - mu * mu + 1e-5f);
    xq[r][tid] = mish_f((qv - mu) * rs * gqv + bgqv);
    s1 = kv; s2 = kv * kv;
    blockReduce2(s1, s2, red);
    mu = s1 * (1.f / C_);
    rs = rsqrtf(s2 * (1.f / C_) - mu * mu + 1e-5f);
    xk[r][tid] = mish_f((kv - mu) * rs * gkv + bgkv);
  }
  __syncthreads();

  // Qp = q@W1, Kp = k@W1 + b1
  float pq[4] = {0,0,0,0}, pk[4] = {0,0,0,0};
  for (int cp = 0; cp < C_; ++cp) {
    float w1 = W1[cp * C_ + tid];
    #pragma unroll
    for (int r = 0; r < 4; ++r) { pq[r] += xq[r][cp] * w1; pk[r] += xk[r][cp] * w1; }
  }
  const float b1v = b1[tid];
  #pragma unroll
  for (int r = 0; r < 4; ++r) {
    Qp[(r0 + r) * C_ + tid] = pq[r];
    Kp[(r0 + r) * C_ + tid] = pk[r] + b1v;
  }
}

// ---------------- W2 -> bf16 fragment-linear repack (32x32x16 layout) ----------------
// W2f[((w*16+ks)*64+l)*8+e] = bf16( W2[k][c] ),  k = ks*16 + (l>>5)*8 + e,
// c = w*32 + (l&31).  k-map sigma identical on A and B sides => correct.
__global__ void __launch_bounds__(256) repack_kernel(
    const float* __restrict__ W2, unsigned short* __restrict__ W2f) {
  int idx = blockIdx.x * 256 + threadIdx.x;  // 65536 total
  int e = idx & 7;
  int l = (idx >> 3) & 63;
  int ks = (idx >> 9) & 15;
  int w = idx >> 13;
  int k = ks * 16 + ((l >> 5) << 3) + e;
  int c = (w << 5) + (l & 31);
  W2f[idx] = f2bf(W2[k * C_ + c]);
}

// ---------------- main fused kernel (pass 1 of 2) ----------------
// grid (512, 2): blockIdx.x = i, blockIdx.y = j-chunk (256 j's). 512 thr = 8 waves.
__global__ void __launch_bounds__(512, 4) attn_kernel(
    const float* __restrict__ dist, const float* __restrict__ v,
    const float* __restrict__ Qp, const float* __restrict__ Kp,
    const unsigned short* __restrict__ W2f,
    const float* __restrict__ gw, const float* __restrict__ bw,
    float* __restrict__ pden, float* __restrict__ pacc) {
  const int tid = threadIdx.x;
  const int i = blockIdx.x;
  const int chunk = blockIdx.y;
  const int j0 = chunk * JPB;
  const int lane = tid & 63, wave = tid >> 6;
  const int jg = tid >> 4, g = tid & 15;   // tphase: 32 j-rows x 16 ch/thread
  const int row = lane & 31, hi = lane >> 5;
  const int cw = (wave << 5) + row;        // this lane's output channel

  // T layout: 16B chunk index (ks*2+hi)*32 + row ; byte = idx*16 ^ ((ks&7)<<4)
  __shared__ __align__(16) unsigned short T[JT * C_];  // 16 KiB
  __shared__ float qpL[C_], gwL[C_], bwL[C_];
  __shared__ float distT[JT];
  char* Tb = reinterpret_cast<char*>(T);

  if (tid < C_) {
    qpL[tid] = Qp[i * C_ + tid];
    gwL[tid] = gw[tid];
    bwL[tid] = bw[tid];
  }

  // resident B fragments: 16 ksteps x 4 VGPR = 64 VGPR (32 channels/wave)
  s8v Bfr[16];
  #pragma unroll
  for (int ks = 0; ks < 16; ++ks)
    Bfr[ks] = *reinterpret_cast<const s8v*>(
        W2f + ((((wave << 4) + ks) * 64 + lane) << 3));

  float den = 0.f, accv = 0.f;
  __syncthreads();  // qpL/gwL/bwL ready

  // write offsets for this thread (ks = g): hi=0 and hi=1 chunks
  const int wb0 = ((((g << 1)    ) << 5) + jg) * 16 ^ ((g & 7) << 4);
  const int wb1 = ((((g << 1) + 1) << 5) + jg) * 16 ^ ((g & 7) << 4);

  for (int jt = 0; jt < JPB / JT; ++jt) {
    const int jb = j0 + jt * JT;
    // ---- T phase: t[j, g*16 .. g*16+15] = mish(LN(Kp[j]-Qp[i])) ----
    {
      const int j = jb + jg;
      const float* kpr = Kp + j * C_ + (g << 4);
      const float* qpr = qpL + (g << 4);
      float d[16];
      float s = 0.f, s2 = 0.f;
      #pragma unroll
      for (int e = 0; e < 16; ++e) {
        float x = kpr[e] - qpr[e];
        d[e] = x; s += x; s2 += x * x;
      }
      #pragma unroll
      for (int mk = 1; mk < 16; mk <<= 1) { s += __shfl_xor(s, mk); s2 += __shfl_xor(s2, mk); }
      float mu = s * (1.f / C_);
      float rs = rsqrtf(s2 * (1.f / C_) - mu * mu + 1e-5f);
      if (g == 0) distT[jg] = dist[j];
      const float* gwp = gwL + (g << 4);
      const float* bwp = bwL + (g << 4);
      u4v p0, p1;
      #pragma unroll
      for (int h = 0; h < 8; ++h) {
        float a = mish_f((d[2*h]   - mu) * rs * gwp[2*h]   + bwp[2*h]);
        float b = mish_f((d[2*h+1] - mu) * rs * gwp[2*h+1] + bwp[2*h+1]);
        // cheap round-to-nearest bf16 (values finite)
        unsigned pa = (__float_as_uint(a) + 0x8000u) >> 16;
        unsigned pb = (__float_as_uint(b) + 0x8000u) & 0xFFFF0000u;
        unsigned pk = pa | pb;
        if (h < 4) p0[h] = pk; else p1[h - 4] = pk;
      }
      *reinterpret_cast<u4v*>(Tb + wb0) = p0;  // c = g*16+0..7   (ks=g, hi=0)
      *reinterpret_cast<u4v*>(Tb + wb1) = p1;  // c = g*16+8..15  (ks=g, hi=1)
    }
    __syncthreads();

    // ---- MFMA: w[32 x 256] = T @ W2 ; this wave: channels wave*32..+31 ----
    f16v wv;
    #pragma unroll
    for (int r = 0; r < 16; ++r) wv[r] = 0.f;
    #pragma unroll
    for (int ks = 0; ks < 16; ++ks) {
      const int off = (((((ks << 1) + hi) << 5) + row) * 16) ^ ((ks & 7) << 4);
      s8v A = *reinterpret_cast<const s8v*>(Tb + off);
      wv = __builtin_amdgcn_mfma_f32_32x32x16_bf16(A, Bfr[ks], wv, 0, 0, 0);
    }

    // ---- max-free softmax accumulate (D layout: col=lane&31,
    //      row=(r&3)+8*(r>>2)+4*(lane>>5), verified m74/m101) ----
    #pragma unroll
    for (int r = 0; r < 16; ++r) {
      const int jj = (r & 3) + ((r >> 2) << 3) + (hi << 2);
      float e = __expf(fminf(wv[r], 60.f)) * distT[jj];
      den += e;
      accv += e * v[(jb + jj) * C_ + cw];
    }
    __syncthreads();  // protect T/distT before next tile's writes
  }

  // halves hold disjoint j-rows of the same channel: one xor-32 merge
  den  += __shfl_xor(den, 32);
  accv += __shfl_xor(accv, 32);
  if (lane < 32) {
    pden[(chunk * N_ + i) * C_ + cw] = den;
    pacc[(chunk * N_ + i) * C_ + cw] = accv;
  }
}

// ---------------- pass 2: merge chunk partials ----------------
__global__ void __launch_bounds__(256) reduce_kernel(
    const float* __restrict__ dist,
    const float* __restrict__ pden, const float* __restrict__ pacc,
    float* __restrict__ out) {
  const int i = blockIdx.x, c = threadIdx.x;
  float den = 0.f, acc = 0.f;
  #pragma unroll
  for (int ch = 0; ch < NCHUNK; ++ch) {
    den += pden[(ch * N_ + i) * C_ + c];
    acc += pacc[(ch * N_ + i) * C_ + c];
  }
  float o = 0.f;
  if (dist[i] > 0.f && den > 0.f) o = acc / den;
  out[i * C_ + c] = o;
}

extern "C" void kernel_launch(void* const* d_in, const int* in_sizes, int n_in,
                              void* d_out, int out_size, void* d_ws, size_t ws_size,
                              hipStream_t stream) {
  const float* feat = (const float*)d_in[0];
  const float* Wq   = (const float*)d_in[1];
  const float* bq   = (const float*)d_in[2];
  const float* gq   = (const float*)d_in[3];
  const float* bgq  = (const float*)d_in[4];
  const float* Wk   = (const float*)d_in[5];
  const float* bk   = (const float*)d_in[6];
  const float* gk   = (const float*)d_in[7];
  const float* bgk  = (const float*)d_in[8];
  const float* Wv   = (const float*)d_in[9];
  const float* bv   = (const float*)d_in[10];
  const float* W1   = (const float*)d_in[11];
  const float* b1   = (const float*)d_in[12];
  const float* gw   = (const float*)d_in[13];
  const float* bw   = (const float*)d_in[14];
  const float* W2   = (const float*)d_in[15];
  // d_in[16] = b2 : cancels exactly in the j-softmax, unused.

  char* ws = (char*)d_ws;
  float* dist = (float*)(ws + 0);            // 512 f32
  float* v    = (float*)(ws + 0x010000);     // 512 KB
  float* Qp   = (float*)(ws + 0x090000);     // 512 KB
  float* Kp   = (float*)(ws + 0x110000);     // 512 KB
  unsigned short* W2f = (unsigned short*)(ws + 0x190000);  // 128 KB
  float* pden = (float*)(ws + 0x1B0000);     // 2*512*256 f32 = 1 MB
  float* pacc = (float*)(ws + 0x2B0000);     // 1 MB

  hipLaunchKernelGGL(prep_kernel, dim3(128), dim3(256), 0, stream,
                     feat, Wq, bq, gq, bgq, Wk, bk, gk, bgk, Wv, bv, W1, b1,
                     dist, v, Qp, Kp);
  hipLaunchKernelGGL(repack_kernel, dim3(256), dim3(256), 0, stream, W2, W2f);
  hipLaunchKernelGGL(attn_kernel, dim3(512, NCHUNK), dim3(512), 0, stream,
                     dist, v, Qp, Kp, W2f, gw, bw, pden, pacc);
  hipLaunchKernelGGL(reduce_kernel, dim3(512), dim3(256), 0, stream,
                     dist, pden, pacc, (float*)d_out);
}

// Round 7
// 166.715 us; speedup vs baseline: 1.2646x; 1.2032x over previous
//
#include <hip/hip_runtime.h>
#include <hip/hip_bf16.h>
#include <math.h>

// Problem: B=1, N=512, C=256, fp32 in/out.
// out[i,c] = sum_j softmax_j( w[i,j,c] ) * v[j,c],  w = mish(LN(Kp[j]-Qp[i])) @ W2  (+b2 cancels)
// Kp = mish(LN(feat@Wk+bk)) @ W1 + b1 ; Qp = mish(LN(feat@Wq+bq)) @ W1 ; v = feat@Wv+bv
// R7 = R6 (32x32x16 MFMA, 8 waves, 2 blocks/CU) with conflict-free LDS:
//   - qpL/gwL/bwL read as f4v (ds_read_b128, 2-way max)
//   - T byte map: chunk*16 ^ ((ks&7)<<6)  -> write quads = all 32, 2 lanes each;
//     read at fixed ks = contiguous 1KB sweep (XOR wave-uniform) -> free.

#define N_ 512
#define C_ 256
#define NCHUNK 2
#define JPB (N_ / NCHUNK)   // 256 j's per block
#define JT 32               // j rows per tile

typedef short s8v __attribute__((ext_vector_type(8)));
typedef float f4v __attribute__((ext_vector_type(4)));
typedef float f16v __attribute__((ext_vector_type(16)));
typedef unsigned int u4v __attribute__((ext_vector_type(4)));

__device__ __forceinline__ unsigned short f2bf(float x) {
  union { __hip_bfloat16 h; unsigned short u; } cv;
  cv.h = __float2bfloat16(x);
  return cv.u;
}

__device__ __forceinline__ float mish_f(float x) {
  // mish(x) = x*tanh(softplus(x)) = x*(y^2-1)/(y^2+1), y = 1+e^x
  if (x > 25.f) return x;  // tanh saturated to 1.0 in fp32
  float y = 1.f + __expf(x);
  float y2 = y * y;
  return x * __fdividef(y2 - 1.f, y2 + 1.f);
}

// block (256 thr) reduction of two values, result broadcast to all threads
__device__ __forceinline__ void blockReduce2(float& a, float& b, float* red) {
  #pragma unroll
  for (int m = 1; m < 64; m <<= 1) { a += __shfl_xor(a, m); b += __shfl_xor(b, m); }
  int lane = threadIdx.x & 63, w = threadIdx.x >> 6;
  if (lane == 0) { red[w] = a; red[4 + w] = b; }
  __syncthreads();
  a = red[0] + red[1] + red[2] + red[3];
  b = red[4] + red[5] + red[6] + red[7];
  __syncthreads();
}

// ---------------- prep: dist, v, Qp, Kp (fp32) ----------------
__global__ void __launch_bounds__(256) prep_kernel(
    const float* __restrict__ feat,
    const float* __restrict__ Wq, const float* __restrict__ bq,
    const float* __restrict__ gq, const float* __restrict__ bgq,
    const float* __restrict__ Wk, const float* __restrict__ bk,
    const float* __restrict__ gk, const float* __restrict__ bgk,
    const float* __restrict__ Wv, const float* __restrict__ bv,
    const float* __restrict__ W1, const float* __restrict__ b1,
    float* __restrict__ dist, float* __restrict__ vout,
    float* __restrict__ Qp, float* __restrict__ Kp) {
  const int tid = threadIdx.x;
  const int r0 = blockIdx.x * 4;
  __shared__ float fL[4][C_];
  __shared__ float xq[4][C_];
  __shared__ float xk[4][C_];
  __shared__ float red[8];

  #pragma unroll
  for (int r = 0; r < 4; ++r) fL[r][tid] = feat[(r0 + r) * C_ + tid];
  __syncthreads();

  // dist = (sum |feat| > 0)
  {
    float a = fabsf(fL[0][tid]), b = fabsf(fL[1][tid]);
    blockReduce2(a, b, red);
    if (tid == 0) { dist[r0 + 0] = a > 0.f ? 1.f : 0.f; dist[r0 + 1] = b > 0.f ? 1.f : 0.f; }
    a = fabsf(fL[2][tid]); b = fabsf(fL[3][tid]);
    blockReduce2(a, b, red);
    if (tid == 0) { dist[r0 + 2] = a > 0.f ? 1.f : 0.f; dist[r0 + 3] = b > 0.f ? 1.f : 0.f; }
  }

  // q/k/v matmuls (fp32)
  float aq[4] = {0,0,0,0}, ak[4] = {0,0,0,0}, av[4] = {0,0,0,0};
  for (int cp = 0; cp < C_; ++cp) {
    float wq = Wq[cp * C_ + tid], wk = Wk[cp * C_ + tid], wv = Wv[cp * C_ + tid];
    #pragma unroll
    for (int r = 0; r < 4; ++r) {
      float f = fL[r][cp];
      aq[r] += f * wq; ak[r] += f * wk; av[r] += f * wv;
    }
  }
  {
    float bvv = bv[tid];
    #pragma unroll
    for (int r = 0; r < 4; ++r) vout[(r0 + r) * C_ + tid] = av[r] + bvv;
  }

  const float bqv = bq[tid], bkv = bk[tid];
  const float gqv = gq[tid], bgqv = bgq[tid], gkv = gk[tid], bgkv = bgk[tid];
  for (int r = 0; r < 4; ++r) {
    float qv = aq[r] + bqv, kv = ak[r] + bkv;
    float s1 = qv, s2 = qv * qv;
    blockReduce2(s1, s2, red);
    float mu = s1 * (1.f / C_);
    float rs = rsqrtf(s2 * (1.f / C_) - mu * mu + 1e-5f);
    xq[r][tid] = mish_f((qv - mu) * rs * gqv + bgqv);
    s1 = kv; s2 = kv * kv;
    blockReduce2(s1, s2, red);
    mu = s1 * (1.f / C_);
    rs = rsqrtf(s2 * (1.f / C_) - mu * mu + 1e-5f);
    xk[r][tid] = mish_f((kv - mu) * rs * gkv + bgkv);
  }
  __syncthreads();

  // Qp = q@W1, Kp = k@W1 + b1
  float pq[4] = {0,0,0,0}, pk[4] = {0,0,0,0};
  for (int cp = 0; cp < C_; ++cp) {
    float w1 = W1[cp * C_ + tid];
    #pragma unroll
    for (int r = 0; r < 4; ++r) { pq[r] += xq[r][cp] * w1; pk[r] += xk[r][cp] * w1; }
  }
  const float b1v = b1[tid];
  #pragma unroll
  for (int r = 0; r < 4; ++r) {
    Qp[(r0 + r) * C_ + tid] = pq[r];
    Kp[(r0 + r) * C_ + tid] = pk[r] + b1v;
  }
}

// ---------------- W2 -> bf16 fragment-linear repack (32x32x16 layout) ----------------
// W2f[((w*16+ks)*64+l)*8+e] = bf16( W2[k][c] ),  k = ks*16 + (l>>5)*8 + e,
// c = w*32 + (l&31).  k-map sigma identical on A and B sides => correct.
__global__ void __launch_bounds__(256) repack_kernel(
    const float* __restrict__ W2, unsigned short* __restrict__ W2f) {
  int idx = blockIdx.x * 256 + threadIdx.x;  // 65536 total
  int e = idx & 7;
  int l = (idx >> 3) & 63;
  int ks = (idx >> 9) & 15;
  int w = idx >> 13;
  int k = ks * 16 + ((l >> 5) << 3) + e;
  int c = (w << 5) + (l & 31);
  W2f[idx] = f2bf(W2[k * C_ + c]);
}

// ---------------- main fused kernel (pass 1 of 2) ----------------
// grid (512, 2): blockIdx.x = i, blockIdx.y = j-chunk (256 j's). 512 thr = 8 waves.
__global__ void __launch_bounds__(512, 4) attn_kernel(
    const float* __restrict__ dist, const float* __restrict__ v,
    const float* __restrict__ Qp, const float* __restrict__ Kp,
    const unsigned short* __restrict__ W2f,
    const float* __restrict__ gw, const float* __restrict__ bw,
    float* __restrict__ pden, float* __restrict__ pacc) {
  const int tid = threadIdx.x;
  const int i = blockIdx.x;
  const int chunk = blockIdx.y;
  const int j0 = chunk * JPB;
  const int lane = tid & 63, wave = tid >> 6;
  const int jg = tid >> 4, g = tid & 15;   // tphase: 32 j-rows x 16 ch/thread
  const int row = lane & 31, hi = lane >> 5;
  const int cw = (wave << 5) + row;        // this lane's output channel

  // T layout: 16B chunk index (ks*2+hi)*32 + row ; byte = idx*16 ^ ((ks&7)<<6)
  __shared__ __align__(16) unsigned short T[JT * C_];  // 16 KiB
  __shared__ __align__(16) float qpL[C_], gwL[C_], bwL[C_];
  __shared__ float distT[JT];
  char* Tb = reinterpret_cast<char*>(T);

  if (tid < C_) {
    qpL[tid] = Qp[i * C_ + tid];
    gwL[tid] = gw[tid];
    bwL[tid] = bw[tid];
  }

  // resident B fragments: 16 ksteps x 4 VGPR = 64 VGPR (32 channels/wave)
  s8v Bfr[16];
  #pragma unroll
  for (int ks = 0; ks < 16; ++ks)
    Bfr[ks] = *reinterpret_cast<const s8v*>(
        W2f + ((((wave << 4) + ks) * 64 + lane) << 3));

  float den = 0.f, accv = 0.f;
  __syncthreads();  // qpL/gwL/bwL ready

  // write offsets for this thread (ks = g): hi=0 and hi=1 chunks
  const int swz = (g & 7) << 6;
  const int wb0 = (((((g << 1)    ) << 5) + jg) << 4) ^ swz;
  const int wb1 = (((((g << 1) + 1) << 5) + jg) << 4) ^ swz;
  const f4v* qp4 = reinterpret_cast<const f4v*>(qpL + (g << 4));
  const f4v* gw4 = reinterpret_cast<const f4v*>(gwL + (g << 4));
  const f4v* bw4 = reinterpret_cast<const f4v*>(bwL + (g << 4));

  for (int jt = 0; jt < JPB / JT; ++jt) {
    const int jb = j0 + jt * JT;
    // ---- T phase: t[j, g*16 .. g*16+15] = mish(LN(Kp[j]-Qp[i])) ----
    {
      const int j = jb + jg;
      const float* kpr = Kp + j * C_ + (g << 4);
      f4v dd[4];
      float s = 0.f, s2 = 0.f;
      #pragma unroll
      for (int m = 0; m < 4; ++m) {
        f4v kk = *reinterpret_cast<const f4v*>(kpr + (m << 2));
        f4v qq = qp4[m];                  // ds_read_b128, 2-way max
        f4v d = kk - qq;
        dd[m] = d;
        #pragma unroll
        for (int e = 0; e < 4; ++e) { s += d[e]; s2 += d[e] * d[e]; }
      }
      #pragma unroll
      for (int mk = 1; mk < 16; mk <<= 1) { s += __shfl_xor(s, mk); s2 += __shfl_xor(s2, mk); }
      float mu = s * (1.f / C_);
      float rs = rsqrtf(s2 * (1.f / C_) - mu * mu + 1e-5f);
      if (g == 0) distT[jg] = dist[j];
      u4v p0, p1;
      #pragma unroll
      for (int m = 0; m < 4; ++m) {
        f4v gg = gw4[m];                  // ds_read_b128, 2-way max
        f4v bb = bw4[m];
        #pragma unroll
        for (int h = 0; h < 2; ++h) {
          float a = mish_f((dd[m][2*h]   - mu) * rs * gg[2*h]   + bb[2*h]);
          float b = mish_f((dd[m][2*h+1] - mu) * rs * gg[2*h+1] + bb[2*h+1]);
          // cheap round-to-nearest bf16 (values finite)
          unsigned pa = (__float_as_uint(a) + 0x8000u) >> 16;
          unsigned pb = (__float_as_uint(b) + 0x8000u) & 0xFFFF0000u;
          unsigned pk = pa | pb;
          if (m < 2) p0[m * 2 + h] = pk; else p1[(m - 2) * 2 + h] = pk;
        }
      }
      *reinterpret_cast<u4v*>(Tb + wb0) = p0;  // c = g*16+0..7   (ks=g, hi=0)
      *reinterpret_cast<u4v*>(Tb + wb1) = p1;  // c = g*16+8..15  (ks=g, hi=1)
    }
    __syncthreads();

    // ---- MFMA: w[32 x 256] = T @ W2 ; this wave: channels wave*32..+31 ----
    f16v wv;
    #pragma unroll
    for (int r = 0; r < 16; ++r) wv[r] = 0.f;
    #pragma unroll
    for (int ks = 0; ks < 16; ++ks) {
      const int off = (((((ks << 1) + hi) << 5) + row) << 4) ^ ((ks & 7) << 6);
      s8v A = *reinterpret_cast<const s8v*>(Tb + off);
      wv = __builtin_amdgcn_mfma_f32_32x32x16_bf16(A, Bfr[ks], wv, 0, 0, 0);
    }

    // ---- max-free softmax accumulate (D layout: col=lane&31,
    //      row=(r&3)+8*(r>>2)+4*(lane>>5), verified m74/m101) ----
    #pragma unroll
    for (int r = 0; r < 16; ++r) {
      const int jj = (r & 3) + ((r >> 2) << 3) + (hi << 2);
      float e = __expf(fminf(wv[r], 60.f)) * distT[jj];
      den += e;
      accv += e * v[(jb + jj) * C_ + cw];
    }
    __syncthreads();  // protect T/distT before next tile's writes
  }

  // halves hold disjoint j-rows of the same channel: one xor-32 merge
  den  += __shfl_xor(den, 32);
  accv += __shfl_xor(accv, 32);
  if (lane < 32) {
    pden[(chunk * N_ + i) * C_ + cw] = den;
    pacc[(chunk * N_ + i) * C_ + cw] = accv;
  }
}

// ---------------- pass 2: merge chunk partials ----------------
__global__ void __launch_bounds__(256) reduce_kernel(
    const float* __restrict__ dist,
    const float* __restrict__ pden, const float* __restrict__ pacc,
    float* __restrict__ out) {
  const int i = blockIdx.x, c = threadIdx.x;
  float den = 0.f, acc = 0.f;
  #pragma unroll
  for (int ch = 0; ch < NCHUNK; ++ch) {
    den += pden[(ch * N_ + i) * C_ + c];
    acc += pacc[(ch * N_ + i) * C_ + c];
  }
  float o = 0.f;
  if (dist[i] > 0.f && den > 0.f) o = acc / den;
  out[i * C_ + c] = o;
}

extern "C" void kernel_launch(void* const* d_in, const int* in_sizes, int n_in,
                              void* d_out, int out_size, void* d_ws, size_t ws_size,
                              hipStream_t stream) {
  const float* feat = (const float*)d_in[0];
  const float* Wq   = (const float*)d_in[1];
  const float* bq   = (const float*)d_in[2];
  const float* gq   = (const float*)d_in[3];
  const float* bgq  = (const float*)d_in[4];
  const float* Wk   = (const float*)d_in[5];
  const float* bk   = (const float*)d_in[6];
  const float* gk   = (const float*)d_in[7];
  const float* bgk  = (const float*)d_in[8];
  const float* Wv   = (const float*)d_in[9];
  const float* bv   = (const float*)d_in[10];
  const float* W1   = (const float*)d_in[11];
  const float* b1   = (const float*)d_in[12];
  const float* gw   = (const float*)d_in[13];
  const float* bw   = (const float*)d_in[14];
  const float* W2   = (const float*)d_in[15];
  // d_in[16] = b2 : cancels exactly in the j-softmax, unused.

  char* ws = (char*)d_ws;
  float* dist = (float*)(ws + 0);            // 512 f32
  float* v    = (float*)(ws + 0x010000);     // 512 KB
  float* Qp   = (float*)(ws + 0x090000);     // 512 KB
  float* Kp   = (float*)(ws + 0x110000);     // 512 KB
  unsigned short* W2f = (unsigned short*)(ws + 0x190000);  // 128 KB
  float* pden = (float*)(ws + 0x1B0000);     // 2*512*256 f32 = 1 MB
  float* pacc = (float*)(ws + 0x2B0000);     // 1 MB

  hipLaunchKernelGGL(prep_kernel, dim3(128), dim3(256), 0, stream,
                     feat, Wq, bq, gq, bgq, Wk, bk, gk, bgk, Wv, bv, W1, b1,
                     dist, v, Qp, Kp);
  hipLaunchKernelGGL(repack_kernel, dim3(256), dim3(256), 0, stream, W2, W2f);
  hipLaunchKernelGGL(attn_kernel, dim3(512, NCHUNK), dim3(512), 0, stream,
                     dist, v, Qp, Kp, W2f, gw, bw, pden, pacc);
  hipLaunchKernelGGL(reduce_kernel, dim3(512), dim3(256), 0, stream,
                     dist, pden, pacc, (float*)d_out);
}